// Round 7
// baseline (94.974 us; speedup 1.0000x reference)
//
#include <hip/hip_runtime.h>
#include <math.h>

// StyleGAN2 2x upsample blur (upfirdn2d, up=2, f=[1,3,3,1], gain=4).
// Separable: g=[0.25,0.75,0.75,0.25] per axis.
//   out[2i]   = 0.25*X[i-1] + 0.75*X[i]
//   out[2i+1] = 0.75*X[i]   + 0.25*X[i+1]
//
// Streaming structure: 2048 blocks = 8 per channel. Each block covers 32
// consecutive input rows; each WAVE owns 8 consecutive input rows and walks
// them with a rolling register row buffer (a,b,c = rows i-1,i,i+1; one new
// float4 load per iteration). Wave writes 16 consecutive output rows =
// 32KB contiguous ascending stream -> long DRAM bursts, minimal re-reads.
//
// Stores: output stride Wo=511 (odd), so each row's float4-alignment shift
// s=(4-(base&3))&3 advances +1 per output row. We dispatch once per wave on
// the initial shift s00 (template) so all rotations/stores are fully static:
// rotate the 8 per-lane values across lanes by S (<=3 shfl), then two
// aligned float4 stores per lane per row + tiny fringes on lanes 0/63.

template<int S>
__device__ __forceinline__ void store_row_s(float* __restrict__ rp, int lane,
                                            int Wo, const float (&v8)[8]) {
    float n0 = 0.f, n1 = 0.f, n2 = 0.f;
    if (S >= 1) n0 = __shfl_down(v8[0], 1);
    if (S >= 2) n1 = __shfl_down(v8[1], 1);
    if (S >= 3) n2 = __shfl_down(v8[2], 1);
    float q[8];
#pragma unroll
    for (int k = 0; k < 8; ++k) {
        int idx = S + k;  // compile-time after unroll
        q[k] = (idx < 8) ? v8[idx] : (idx == 8 ? n0 : (idx == 9 ? n1 : n2));
    }
    int c0 = S + 8 * lane;  // 16B-aligned within row by construction
    if (lane < 63) {
        *(float4*)(rp + c0)     = make_float4(q[0], q[1], q[2], q[3]);
        *(float4*)(rp + c0 + 4) = make_float4(q[4], q[5], q[6], q[7]);
    } else {
        *(float4*)(rp + c0) = make_float4(q[0], q[1], q[2], q[3]);
        if (c0 + 4 < Wo) rp[c0 + 4] = q[4];
        if (c0 + 5 < Wo) rp[c0 + 5] = q[5];
        if (c0 + 6 < Wo) rp[c0 + 6] = q[6];
        if (c0 + 7 < Wo) rp[c0 + 7] = q[7];
    }
    if (S > 0 && lane == 0) {   // left fringe cols 0..S-1
        rp[0] = v8[0];
        if (S > 1) rp[1] = v8[1];
        if (S > 2) rp[2] = v8[2];
    }
}

template<int S00>
__device__ __forceinline__ void run_wave(const float4* __restrict__ xr,
                                         float* __restrict__ out, size_t obase,
                                         int base, int lane,
                                         int H, int Ho, int Wo) {
    int am = base - 1 < 0 ? 0 : base - 1;
    float4 a = xr[am * 64 + lane];
    float4 b = xr[base * 64 + lane];
    float4 c = xr[(base + 1) * 64 + lane];   // base+1 <= 249 < H always

#pragma unroll
    for (int k = 0; k < 8; ++k) {
        int i = base + k;
        float4 d = c;
        if (k < 7) {                          // prefetch row i+2 (clamped)
            int nr = i + 2 > H - 1 ? H - 1 : i + 2;
            d = xr[nr * 64 + lane];
        }
        float w0 = (i > 0)     ? 0.25f : 0.0f;
        float wp = (i < H - 1) ? 0.25f : 0.0f;

        float ve[4], vo[4];
        ve[0] = w0 * a.x + 0.75f * b.x;  vo[0] = 0.75f * b.x + wp * c.x;
        ve[1] = w0 * a.y + 0.75f * b.y;  vo[1] = 0.75f * b.y + wp * c.y;
        ve[2] = w0 * a.z + 0.75f * b.z;  vo[2] = 0.75f * b.z + wp * c.z;
        ve[3] = w0 * a.w + 0.75f * b.w;  vo[3] = 0.75f * b.w + wp * c.w;

        float vem = __shfl_up(ve[3], 1);
        float vom = __shfl_up(vo[3], 1);
        if (lane == 0) { vem = 0.f; vom = 0.f; }   // col -1 contributes 0
        float vep = __shfl_down(ve[0], 1);         // lane63: garbage, never stored
        float vop = __shfl_down(vo[0], 1);

        float e8[8], o8[8];
        e8[0] = 0.25f * vem   + 0.75f * ve[0];  o8[0] = 0.25f * vom   + 0.75f * vo[0];
        e8[1] = 0.75f * ve[0] + 0.25f * ve[1];  o8[1] = 0.75f * vo[0] + 0.25f * vo[1];
        e8[2] = 0.25f * ve[0] + 0.75f * ve[1];  o8[2] = 0.25f * vo[0] + 0.75f * vo[1];
        e8[3] = 0.75f * ve[1] + 0.25f * ve[2];  o8[3] = 0.75f * vo[1] + 0.25f * vo[2];
        e8[4] = 0.25f * ve[1] + 0.75f * ve[2];  o8[4] = 0.25f * vo[1] + 0.75f * vo[2];
        e8[5] = 0.75f * ve[2] + 0.25f * ve[3];  o8[5] = 0.75f * vo[2] + 0.25f * vo[3];
        e8[6] = 0.25f * ve[2] + 0.75f * ve[3];  o8[6] = 0.25f * vo[2] + 0.75f * vo[3];
        e8[7] = 0.75f * ve[3] + 0.25f * vep;    o8[7] = 0.75f * vo[3] + 0.25f * vop;

        float* re = out + obase + (size_t)(2 * i) * Wo;
        float* ro = re + Wo;
        // shift advances +1 per output row; period-2 pattern over iterations
        if ((k & 1) == 0) {
            store_row_s<S00>(re, lane, Wo, e8);
            if (2 * i + 1 < Ho) store_row_s<(S00 + 1) & 3>(ro, lane, Wo, o8);
        } else {
            store_row_s<(S00 + 2) & 3>(re, lane, Wo, e8);
            if (2 * i + 1 < Ho) store_row_s<(S00 + 3) & 3>(ro, lane, Wo, o8);
        }
        a = b; b = c; c = d;
    }
}

__global__ __launch_bounds__(256) void blur_up2_kernel(
    const float* __restrict__ x, float* __restrict__ out,
    int H, int W, int Ho, int Wo) {
    int lane = threadIdx.x;                  // 0..63
    int wv = threadIdx.y;                    // 0..3
    int bid = blockIdx.x;                    // 0..2047
    int nc = bid >> 3;                       // channel
    int base = (bid & 7) * 32 + wv * 8;      // this wave's 8 input rows

    const float4* xr = (const float4*)(x + (size_t)nc * H * W);
    size_t obase = (size_t)nc * Ho * Wo;

    size_t rbase0 = obase + (size_t)(2 * base) * Wo;
    int s00 = (int)((4 - (rbase0 & 3)) & 3);  // wave-uniform
    switch (s00) {
        case 0:  run_wave<0>(xr, out, obase, base, lane, H, Ho, Wo); break;
        case 1:  run_wave<1>(xr, out, obase, base, lane, H, Ho, Wo); break;
        case 2:  run_wave<2>(xr, out, obase, base, lane, H, Ho, Wo); break;
        default: run_wave<3>(xr, out, obase, base, lane, H, Ho, Wo); break;
    }
}

extern "C" void kernel_launch(void* const* d_in, const int* in_sizes, int n_in,
                              void* d_out, int out_size, void* d_ws, size_t ws_size,
                              hipStream_t stream) {
    const float* x = (const float*)d_in[0];
    float* out = (float*)d_out;

    const int H = 256, W = 256;
    int NC = in_sizes[0] / (H * W);  // 256

    int hw_out = out_size / NC;
    int Wo = (int)(sqrt((double)hw_out) + 0.5);
    int Ho = hw_out / Wo;

    dim3 block(64, 4);
    dim3 grid(8 * NC);
    blur_up2_kernel<<<grid, block, 0, stream>>>(x, out, H, W, Ho, Wo);
}

// Round 8
// 80.434 us; speedup vs baseline: 1.1808x; 1.1808x over previous
//
#include <hip/hip_runtime.h>
#include <math.h>

// StyleGAN2 2x upsample blur (upfirdn2d, up=2, f=[1,3,3,1], gain=4).
// Separable: g=[0.25,0.75,0.75,0.25]:
//   out[2i]   = 0.25*X[i-1] + 0.75*X[i]
//   out[2i+1] = 0.75*X[i]   + 0.25*X[i+1]
//
// Wave = one input row i -> output rows {2i, 2i+1}. Store-side layout is
// chosen so EVERY store instruction is fully line-dense (16B/lane stride):
// lane l owns out cols [S+4l, S+4l+4) (window 1) and [S+256+4l, ...) (window
// 2) of each row, where S = (-(row base)) mod 4 is the row's float4 alignment
// shift (wave-uniform, templated; odd row shift = S_even+1 mod 4).
// Feed: lane loads float2 at input cols 2l (w1) and 128+2l (w2) for rows
// i-1, i, i+1 (dense 512B/inst). Vertical blend in regs; horizontal needs
// v[L-1], v[L+2], v[L+3] -> __shfl +-1 within the wave, plus 2 cross-window
// lane-0/63 broadcasts. Fringe cols [0,S) on lane 0; ragged right edge on
// lane 63 (scalar dwords). Rationale: partial-line store instructions cause
// read-for-ownership HBM fetches (~268MB hidden reads in R6/R7).

// out cols 2L+S .. 2L+S+3 from vertical-blend values v0=v[L], v1=v[L+1],
// vm1=v[L-1], vp0=v[L+2], vp1=v[L+3].
template<int S>
__device__ __forceinline__ void hblend(float v0, float v1, float vm1,
                                       float vp0, float vp1, float q[4]) {
    if (S == 0) {
        q[0] = 0.25f*vm1 + 0.75f*v0;
        q[1] = 0.75f*v0  + 0.25f*v1;
        q[2] = 0.25f*v0  + 0.75f*v1;
        q[3] = 0.75f*v1  + 0.25f*vp0;
    } else if (S == 1) {
        q[0] = 0.75f*v0  + 0.25f*v1;
        q[1] = 0.25f*v0  + 0.75f*v1;
        q[2] = 0.75f*v1  + 0.25f*vp0;
        q[3] = 0.25f*v1  + 0.75f*vp0;
    } else if (S == 2) {
        q[0] = 0.25f*v0  + 0.75f*v1;
        q[1] = 0.75f*v1  + 0.25f*vp0;
        q[2] = 0.25f*v1  + 0.75f*vp0;
        q[3] = 0.75f*vp0 + 0.25f*vp1;
    } else {
        q[0] = 0.75f*v1  + 0.25f*vp0;
        q[1] = 0.25f*v1  + 0.75f*vp0;
        q[2] = 0.75f*vp0 + 0.25f*vp1;
        q[3] = 0.25f*vp0 + 0.75f*vp1;
    }
}

template<int S>
__device__ __forceinline__ void store_row(float* __restrict__ rp, int lane,
                                          int Wo, const float q1[4],
                                          const float q2[4],
                                          float v0lane, float v1lane) {
    // window 1: cols S+4l .. S+4l+3 (max S+255 < Wo always)
    *(float4*)(rp + S + 4 * lane) = make_float4(q1[0], q1[1], q1[2], q1[3]);
    // window 2: cols S+256+4l .. +3, ragged at the right edge
    int c0 = S + 256 + 4 * lane;
    if (c0 + 3 < Wo) {
        *(float4*)(rp + c0) = make_float4(q2[0], q2[1], q2[2], q2[3]);
    } else {
        if (c0     < Wo) rp[c0]     = q2[0];
        if (c0 + 1 < Wo) rp[c0 + 1] = q2[1];
        if (c0 + 2 < Wo) rp[c0 + 2] = q2[2];
        if (c0 + 3 < Wo) rp[c0 + 3] = q2[3];
    }
    // fringe cols [0, S): uses lane 0's v[0], v[1] (v[-1] contributes 0)
    if (S > 0 && lane == 0) {
        rp[0] = 0.75f * v0lane;
        if (S > 1) rp[1] = 0.75f * v0lane + 0.25f * v1lane;
        if (S > 2) rp[2] = 0.25f * v0lane + 0.75f * v1lane;
    }
}

template<int SE>
__device__ __forceinline__ void row_pair(
    const float* __restrict__ xp, float* __restrict__ out, size_t be,
    int lane, int i, int H, int W, int Ho, int Wo) {
    constexpr int SO = (SE + 1) & 3;
    int im = i > 0 ? i - 1 : 0;
    int ip = i < H - 1 ? i + 1 : H - 1;
    const float2* ra = (const float2*)(xp + im * W);
    const float2* rb = (const float2*)(xp + i  * W);
    const float2* rc = (const float2*)(xp + ip * W);
    float2 a1 = ra[lane],      b1 = rb[lane],      c1 = rc[lane];
    float2 a2 = ra[64 + lane], b2 = rb[64 + lane], c2 = rc[64 + lane];
    float w0 = (i > 0)     ? 0.25f : 0.0f;   // row masks folded into weights
    float wp = (i < H - 1) ? 0.25f : 0.0f;

    // vertical blends: E = out row 2i, O = out row 2i+1; windows 1,2
    float ve10 = w0*a1.x + 0.75f*b1.x, ve11 = w0*a1.y + 0.75f*b1.y;
    float ve20 = w0*a2.x + 0.75f*b2.x, ve21 = w0*a2.y + 0.75f*b2.y;
    float vo10 = 0.75f*b1.x + wp*c1.x, vo11 = 0.75f*b1.y + wp*c1.y;
    float vo20 = 0.75f*b2.x + wp*c2.x, vo21 = 0.75f*b2.y + wp*c2.y;

    float t;
    // halos, E row, window 1 (v indices L=2l): vm1=v[L-1], vp0=v[L+2], vp1=v[L+3]
    float vm1e1 = __shfl_up(ve11, 1);   if (lane == 0)  vm1e1 = 0.f;
    float vp0e1 = __shfl_down(ve10, 1);
    t = __shfl(ve20, 0);                if (lane == 63) vp0e1 = t;
    float vp1e1 = __shfl_down(ve11, 1);
    t = __shfl(ve21, 0);                if (lane == 63) vp1e1 = t;
    // E row, window 2 (L = 128+2l)
    float vm1e2 = __shfl_up(ve21, 1);
    t = __shfl(ve11, 63);               if (lane == 0)  vm1e2 = t;
    float vp0e2 = __shfl_down(ve20, 1); if (lane == 63) vp0e2 = 0.f;  // masked
    float vp1e2 = __shfl_down(ve21, 1); if (lane == 63) vp1e2 = 0.f;  // masked
    // O row, window 1
    float vm1o1 = __shfl_up(vo11, 1);   if (lane == 0)  vm1o1 = 0.f;
    float vp0o1 = __shfl_down(vo10, 1);
    t = __shfl(vo20, 0);                if (lane == 63) vp0o1 = t;
    float vp1o1 = __shfl_down(vo11, 1);
    t = __shfl(vo21, 0);                if (lane == 63) vp1o1 = t;
    // O row, window 2
    float vm1o2 = __shfl_up(vo21, 1);
    t = __shfl(vo11, 63);               if (lane == 0)  vm1o2 = t;
    float vp0o2 = __shfl_down(vo20, 1); if (lane == 63) vp0o2 = 0.f;
    float vp1o2 = __shfl_down(vo21, 1); if (lane == 63) vp1o2 = 0.f;

    float q1[4], q2[4];
    float* re = out + be;
    hblend<SE>(ve10, ve11, vm1e1, vp0e1, vp1e1, q1);
    hblend<SE>(ve20, ve21, vm1e2, vp0e2, vp1e2, q2);
    store_row<SE>(re, lane, Wo, q1, q2, ve10, ve11);

    if (2 * i + 1 < Ho) {
        float* ro = re + Wo;
        hblend<SO>(vo10, vo11, vm1o1, vp0o1, vp1o1, q1);
        hblend<SO>(vo20, vo21, vm1o2, vp0o2, vp1o2, q2);
        store_row<SO>(ro, lane, Wo, q1, q2, vo10, vo11);
    }
}

__global__ __launch_bounds__(256) void blur_up2_kernel(
    const float* __restrict__ x, float* __restrict__ out,
    int H, int W, int Ho, int Wo) {
    int lane = threadIdx.x;                  // 0..63
    int i = blockIdx.y * 4 + threadIdx.y;    // input row
    int nc = blockIdx.z;
    if (i >= H) return;

    const float* xp = x + (size_t)nc * H * W;
    size_t be = (size_t)nc * Ho * Wo + (size_t)(2 * i) * Wo;
    int S = (int)((4 - (be & 3)) & 3);       // wave-uniform
    switch (S) {
        case 0:  row_pair<0>(xp, out, be, lane, i, H, W, Ho, Wo); break;
        case 1:  row_pair<1>(xp, out, be, lane, i, H, W, Ho, Wo); break;
        case 2:  row_pair<2>(xp, out, be, lane, i, H, W, Ho, Wo); break;
        default: row_pair<3>(xp, out, be, lane, i, H, W, Ho, Wo); break;
    }
}

extern "C" void kernel_launch(void* const* d_in, const int* in_sizes, int n_in,
                              void* d_out, int out_size, void* d_ws, size_t ws_size,
                              hipStream_t stream) {
    const float* x = (const float*)d_in[0];
    float* out = (float*)d_out;

    const int H = 256, W = 256;
    int NC = in_sizes[0] / (H * W);  // 256

    int hw_out = out_size / NC;
    int Wo = (int)(sqrt((double)hw_out) + 0.5);
    int Ho = hw_out / Wo;

    dim3 block(64, 4);
    dim3 grid(1, (H + 3) / 4, NC);
    blur_up2_kernel<<<grid, block, 0, stream>>>(x, out, H, W, Ho, Wo);
}